// Round 3
// baseline (406.773 us; speedup 1.0000x reference)
//
#include <hip/hip_runtime.h>
#include <hip/hip_bf16.h>

typedef unsigned short u16;
typedef __attribute__((ext_vector_type(8))) short bf16x8;   // 8 bf16 = 4 VGPRs
typedef __attribute__((ext_vector_type(4))) float f32x4;

#define NBG   5000
#define NPID  5532
#define NTOT  15532      // 5000 + 5532 + 5000
#define FEAT  256
#define BATCH 4096
#define SCALE_LOG2E 43.280851226668994f   // 30 * log2(e)

// ws float layout:
// [0, 4096)      sum_bg per row
// [4096, 8192)   sum_nb per row
// [8192] det_acc   [8193] oim_acc   [8194] n_valid
#define WS_FLOATS (2 * BATCH + 3)

__device__ __forceinline__ void atomic_add_f(float* p, float v) {
    __hip_atomic_fetch_add(p, v, __ATOMIC_RELAXED, __HIP_MEMORY_SCOPE_AGENT);
}

__device__ __forceinline__ u16 f2bf(float f) {
    return (u16)__bfloat16_as_ushort(__float2bfloat16(f));
}

// Convert 8 consecutive f32 (two float4 vector loads) -> one bf16x8 fragment.
__device__ __forceinline__ bf16x8 load_cvt8(const float* __restrict__ p) {
    f32x4 lo = *(const f32x4*)(p);
    f32x4 hi = *(const f32x4*)(p + 4);
    bf16x8 r;
    r[0] = (short)f2bf(lo[0]); r[1] = (short)f2bf(lo[1]);
    r[2] = (short)f2bf(lo[2]); r[3] = (short)f2bf(lo[3]);
    r[4] = (short)f2bf(hi[0]); r[5] = (short)f2bf(hi[1]);
    r[6] = (short)f2bf(hi[2]); r[7] = (short)f2bf(hi[3]);
    return r;
}

// -------- Stage 1: fused GEMM + exp-sum reduction --------------------------
// Block: 256 threads = 4 waves. Wave w covers rows [blockIdx.y*128 + w*32, +32).
// blockIdx.x selects a chunk of 16 col-tiles (16 cols each -> 256 cols/chunk).
__global__ __launch_bounds__(256) void score_kernel(
    const float* __restrict__ inputs, const float* __restrict__ lut,
    const float* __restrict__ cq, const float* __restrict__ cqb,
    float* __restrict__ sum_bg, float* __restrict__ sum_nb)
{
    const int wave = threadIdx.x >> 6;
    const int lane = threadIdx.x & 63;
    const int l15  = lane & 15;
    const int quad = lane >> 4;
    const int row0 = blockIdx.y * 128 + wave * 32;
    const int tile0 = blockIdx.x * 16;

    // A fragments for 32 rows (2 sets of 16), all 8 K-steps, converted once.
    bf16x8 a0[8], a1[8];
    {
        const float* ar0 = inputs + (row0 + l15) * FEAT + quad * 8;
        const float* ar1 = ar0 + 16 * FEAT;
        #pragma unroll
        for (int kk = 0; kk < 8; ++kk) {
            a0[kk] = load_cvt8(ar0 + kk * 32);
            a1[kk] = load_cvt8(ar1 + kk * 32);
        }
    }

    float pbg[8] = {0.f,0.f,0.f,0.f,0.f,0.f,0.f,0.f};
    float pnb[8] = {0.f,0.f,0.f,0.f,0.f,0.f,0.f,0.f};

    #pragma unroll 1
    for (int t = 0; t < 16; ++t) {
        const int colbase = (tile0 + t) * 16;
        if (colbase >= NTOT) break;           // uniform across block
        const int n  = colbase + l15;
        const int nc = n < NTOT ? n : NTOT - 1;
        const float* brow;
        if (nc < NBG)             brow = cqb + nc * FEAT;
        else if (nc < NBG + NPID) brow = lut + (nc - NBG) * FEAT;
        else                      brow = cq  + (nc - NBG - NPID) * FEAT;
        brow += quad * 8;

        f32x4 c0 = {0.f,0.f,0.f,0.f};
        f32x4 c1 = {0.f,0.f,0.f,0.f};
        #pragma unroll
        for (int kk = 0; kk < 8; ++kk) {
            bf16x8 b = load_cvt8(brow + kk * 32);
            c0 = __builtin_amdgcn_mfma_f32_16x16x32_bf16(a0[kk], b, c0, 0, 0, 0);
            c1 = __builtin_amdgcn_mfma_f32_16x16x32_bf16(a1[kk], b, c1, 0, 0, 0);
        }

        const bool okc  = n < NTOT;
        const bool isbg = n < NBG;
        #pragma unroll
        for (int r = 0; r < 4; ++r) {
            float e0 = exp2f(c0[r] * SCALE_LOG2E);
            float e1 = exp2f(c1[r] * SCALE_LOG2E);
            e0 = okc ? e0 : 0.f;
            e1 = okc ? e1 : 0.f;
            pbg[r]     += isbg ? e0 : 0.f;
            pnb[r]     += isbg ? 0.f : e0;
            pbg[4 + r] += isbg ? e1 : 0.f;
            pnb[4 + r] += isbg ? 0.f : e1;
        }
    }

    // Reduce across the 16 lanes of each quad (the 16 columns of D).
    #pragma unroll
    for (int off = 1; off < 16; off <<= 1) {
        #pragma unroll
        for (int i = 0; i < 8; ++i) {
            pbg[i] += __shfl_xor(pbg[i], off);
            pnb[i] += __shfl_xor(pnb[i], off);
        }
    }
    if (l15 == 0) {
        #pragma unroll
        for (int s = 0; s < 2; ++s) {
            #pragma unroll
            for (int r = 0; r < 4; ++r) {
                const int row = row0 + s * 16 + quad * 4 + r;
                atomic_add_f(&sum_bg[row], pbg[s * 4 + r]);
                atomic_add_f(&sum_nb[row], pnb[s * 4 + r]);
            }
        }
    }
}

// -------- Stage 2: per-row finalize (cls_score, loss terms) ----------------
// One wave per row; 4 rows per block.
__global__ __launch_bounds__(256) void finalize_kernel(
    const float* __restrict__ inputs, const int* __restrict__ roi_label,
    const float* __restrict__ lut,
    const float* __restrict__ sum_bg, const float* __restrict__ sum_nb,
    float* __restrict__ accums, float* __restrict__ out)
{
    __shared__ float s_det[4], s_oim[4], s_nv[4];
    const int wid  = threadIdx.x >> 6;
    const int lane = threadIdx.x & 63;
    const int row  = blockIdx.x * 4 + wid;
    const int r    = roi_label[row];

    // dot(inputs[row], lut[clamp(r)]) across the wave (4 elems/lane).
    // Round both sides to bf16 to match the score kernel's quantization.
    float dot = 0.f;
    {
        const int rc = r < 0 ? 0 : r;
        const f32x4 xi = *(const f32x4*)(inputs + row * FEAT + lane * 4);
        const f32x4 li = *(const f32x4*)(lut + rc * FEAT + lane * 4);
        #pragma unroll
        for (int j = 0; j < 4; ++j) {
            float a = __bfloat162float(__float2bfloat16(xi[j]));
            float b = __bfloat162float(__float2bfloat16(li[j]));
            dot += a * b;
        }
    }
    #pragma unroll
    for (int off = 32; off > 0; off >>= 1) dot += __shfl_xor(dot, off);

    if (lane == 0) {
        const float sbg = sum_bg[row];
        const float snb = sum_nb[row];
        const float inv = 1.f / (sbg + snb);
        const float cls0 = sbg * inv;
        const float cls1 = snb * inv;
        out[2 * row]     = cls0;
        out[2 * row + 1] = cls1;

        // det loss: det_label = (r >= -1) ? 1 : 0
        const float cs = (r >= -1) ? cls1 : cls0;
        const float om = 1.f - cs;
        s_det[wid] = -(0.25f * om * om * logf(cs)) * (1.f / (float)BATCH);
        s_nv[wid]  = (r >= -1) ? 1.f : 0.f;

        float rl = 0.f;
        if (r >= 0) {
            const float slab = 30.f * dot;
            const float logp = slab - logf(snb);   // log_softmax over non-bg
            const float p    = expf(logp);
            const float om2  = 1.f - p;
            rl = -(0.25f * om2 * om2 * logp) * cls1 * cls1;
        }
        s_oim[wid] = rl;
    }
    __syncthreads();
    if (threadIdx.x == 0) {
        atomic_add_f(&accums[0], s_det[0] + s_det[1] + s_det[2] + s_det[3]);
        atomic_add_f(&accums[1], s_oim[0] + s_oim[1] + s_oim[2] + s_oim[3]);
        atomic_add_f(&accums[2], s_nv[0] + s_nv[1] + s_nv[2] + s_nv[3]);
    }
}

// -------- Stage 3: scalar outputs ------------------------------------------
__global__ void scalars_kernel(const float* __restrict__ accums,
                               float* __restrict__ out)
{
    if (threadIdx.x == 0) {
        float nv = accums[2];
        if (nv < 1.f) nv = 1.f;
        out[2 * BATCH]     = accums[0];
        out[2 * BATCH + 1] = accums[1] / nv;
    }
}

extern "C" void kernel_launch(void* const* d_in, const int* in_sizes, int n_in,
                              void* d_out, int out_size, void* d_ws, size_t ws_size,
                              hipStream_t stream)
{
    const float* inputs = (const float*)d_in[0];
    const int*   roi    = (const int*)d_in[1];
    const float* lut    = (const float*)d_in[2];
    const float* cq     = (const float*)d_in[3];
    const float* cqb    = (const float*)d_in[4];
    float* W = (float*)d_ws;
    float* out = (float*)d_out;

    hipMemsetAsync(d_ws, 0, WS_FLOATS * sizeof(float), stream);

    // 61 col-chunks of 256 cols (15532 -> 971 tiles of 16, padded)
    dim3 g1(61, 32);
    score_kernel<<<g1, 256, 0, stream>>>(inputs, lut, cq, cqb, W, W + BATCH);

    finalize_kernel<<<BATCH / 4, 256, 0, stream>>>(inputs, roi, lut,
                                                   W, W + BATCH, W + 2 * BATCH, out);

    scalars_kernel<<<1, 64, 0, stream>>>(W + 2 * BATCH, out);
}

// Round 4
// 370.646 us; speedup vs baseline: 1.0975x; 1.0975x over previous
//
#include <hip/hip_runtime.h>
#include <hip/hip_bf16.h>

typedef unsigned short u16;
typedef __attribute__((ext_vector_type(8))) short bf16x8;   // 8 bf16 = 4 VGPRs
typedef __attribute__((ext_vector_type(4))) short bf16x4;
typedef __attribute__((ext_vector_type(4))) float f32x4;

#define NBG   5000
#define NPID  5532
#define NTOT  15532      // 5000 + 5532 + 5000
#define FEAT  256
#define BATCH 4096
#define SCALE_LOG2E 43.280851226668994f   // 30 * log2(e)
#define LPITCH 264       // shorts per staged line: 256 bf16 + 8 pad = 528 B
                         // (528 B stride = +4 banks/line -> worst 2-way, free)

// ws float layout:
// [0,4096) sum_bg | [4096,8192) sum_nb | [8192] det [8193] oim [8194] nvalid
// [8195] ticket (uint)
#define WS_FLOATS (2 * BATCH + 4)

__device__ __forceinline__ void atomic_add_f(float* p, float v) {
    __hip_atomic_fetch_add(p, v, __ATOMIC_RELAXED, __HIP_MEMORY_SCOPE_AGENT);
}
__device__ __forceinline__ short f2bf(float f) {
    return (short)__bfloat16_as_ushort(__float2bfloat16(f));
}

// -------- Stage 1: fused GEMM + exp-sum reduction --------------------------
// Block: 256 threads = 4 waves. Covers 256 rows x 256 cols.
// Wave w owns rows [rowbase + w*64, +64) as 4 register A-frag sets.
// B staged 32 cols/stage through one 16.5 KB LDS buffer (f32->bf16 on the fly),
// with register prefetch of the next stage overlapping the MFMA consume.
__global__ __launch_bounds__(256, 2) void score_kernel(
    const float* __restrict__ inputs, const float* __restrict__ lut,
    const float* __restrict__ cq, const float* __restrict__ cqb,
    float* __restrict__ sum_bg, float* __restrict__ sum_nb)
{
    __shared__ __align__(16) short lds[32 * LPITCH];
    const int wave = threadIdx.x >> 6;
    const int lane = threadIdx.x & 63;
    const int l15  = lane & 15;
    const int quad = lane >> 4;
    const int rowbase = blockIdx.y * 256;
    const int colbase = blockIdx.x * 256;

    auto colptr = [&](int col) -> const float* {
        const int nc = col < NTOT ? col : NTOT - 1;   // clamp; masked in epilogue
        if (nc < NBG)        return cqb + nc * FEAT;
        if (nc < NBG + NPID) return lut + (nc - NBG) * FEAT;
        return cq + (nc - NBG - NPID) * FEAT;
    };

    // ---- A: stage 256 rows (8 chunks of 32) via LDS into register frags ----
    bf16x8 afrag[4][8];
    #pragma unroll 1
    for (int c = 0; c < 8; ++c) {
        __syncthreads();                        // prior chunk's frag reads done
        #pragma unroll
        for (int i = 0; i < 8; ++i) {
            const int lr = i * 4 + wave;        // wave-uniform row
            const f32x4 v = *(const f32x4*)(inputs + (size_t)(rowbase + c * 32 + lr) * FEAT + lane * 4);
            bf16x4 h = { f2bf(v[0]), f2bf(v[1]), f2bf(v[2]), f2bf(v[3]) };
            *(bf16x4*)(&lds[lr * LPITCH + lane * 4]) = h;
        }
        __syncthreads();
        if ((c >> 1) == wave) {                 // this chunk holds my rows
            const int half = c & 1;             // sets half*2, half*2+1
            #pragma unroll
            for (int j2 = 0; j2 < 2; ++j2) {
                const int lr = j2 * 16 + l15;
                #pragma unroll
                for (int kk = 0; kk < 8; ++kk)
                    afrag[half * 2 + j2][kk] =
                        *(const bf16x8*)(&lds[lr * LPITCH + kk * 32 + quad * 8]);
            }
        }
    }

    // ---- B: stages of 32 cols, reg-prefetch pipeline ----
    float pbg[16], pnb[16];
    #pragma unroll
    for (int i = 0; i < 16; ++i) { pbg[i] = 0.f; pnb[i] = 0.f; }

    const int ncols = NTOT - colbase;                       // >= 172 always
    const int nstages = ncols >= 256 ? 8 : (ncols + 31) / 32;

    f32x4 R[8];
    #pragma unroll
    for (int i = 0; i < 8; ++i)
        R[i] = *(const f32x4*)(colptr(colbase + i * 4 + wave) + lane * 4);

    #pragma unroll 1
    for (int s = 0; s < nstages; ++s) {
        __syncthreads();                        // previous consume done
        #pragma unroll
        for (int i = 0; i < 8; ++i) {
            const int lc = i * 4 + wave;
            bf16x4 h = { f2bf(R[i][0]), f2bf(R[i][1]), f2bf(R[i][2]), f2bf(R[i][3]) };
            *(bf16x4*)(&lds[lc * LPITCH + lane * 4]) = h;
        }
        if (s + 1 < nstages) {                  // prefetch next stage into regs
            const int cb = colbase + (s + 1) * 32;
            #pragma unroll
            for (int i = 0; i < 8; ++i)
                R[i] = *(const f32x4*)(colptr(cb + i * 4 + wave) + lane * 4);
        }
        __syncthreads();                        // stage visible

        #pragma unroll
        for (int st = 0; st < 2; ++st) {
            const int lc = st * 16 + l15;
            f32x4 cc[4];
            #pragma unroll
            for (int j = 0; j < 4; ++j) cc[j] = f32x4{0.f, 0.f, 0.f, 0.f};
            #pragma unroll
            for (int kk = 0; kk < 8; ++kk) {
                const bf16x8 b = *(const bf16x8*)(&lds[lc * LPITCH + kk * 32 + quad * 8]);
                cc[0] = __builtin_amdgcn_mfma_f32_16x16x32_bf16(afrag[0][kk], b, cc[0], 0, 0, 0);
                cc[1] = __builtin_amdgcn_mfma_f32_16x16x32_bf16(afrag[1][kk], b, cc[1], 0, 0, 0);
                cc[2] = __builtin_amdgcn_mfma_f32_16x16x32_bf16(afrag[2][kk], b, cc[2], 0, 0, 0);
                cc[3] = __builtin_amdgcn_mfma_f32_16x16x32_bf16(afrag[3][kk], b, cc[3], 0, 0, 0);
            }
            const int n = colbase + s * 32 + st * 16 + l15;
            const bool okc  = n < NTOT;
            const bool isbg = n < NBG;
            #pragma unroll
            for (int j = 0; j < 4; ++j) {
                #pragma unroll
                for (int r = 0; r < 4; ++r) {
                    float e = exp2f(cc[j][r] * SCALE_LOG2E);
                    e = okc ? e : 0.f;
                    pbg[j * 4 + r] += isbg ? e : 0.f;
                    pnb[j * 4 + r] += isbg ? 0.f : e;
                }
            }
        }
    }

    // Reduce across the 16 lanes of each quad (the 16 columns of D).
    #pragma unroll
    for (int off = 1; off < 16; off <<= 1) {
        #pragma unroll
        for (int i = 0; i < 16; ++i) {
            pbg[i] += __shfl_xor(pbg[i], off);
            pnb[i] += __shfl_xor(pnb[i], off);
        }
    }
    if (l15 == 0) {
        #pragma unroll
        for (int j = 0; j < 4; ++j) {
            #pragma unroll
            for (int r = 0; r < 4; ++r) {
                const int row = rowbase + wave * 64 + j * 16 + quad * 4 + r;
                atomic_add_f(&sum_bg[row], pbg[j * 4 + r]);
                atomic_add_f(&sum_nb[row], pnb[j * 4 + r]);
            }
        }
    }
}

// -------- Stage 2: per-row finalize + last-block scalar fold ---------------
// One wave per row; 4 rows per block.
__global__ __launch_bounds__(256) void finalize_kernel(
    const float* __restrict__ inputs, const int* __restrict__ roi_label,
    const float* __restrict__ lut,
    const float* __restrict__ sum_bg, const float* __restrict__ sum_nb,
    float* __restrict__ accums, unsigned int* __restrict__ ticket,
    float* __restrict__ out)
{
    __shared__ float s_det[4], s_oim[4], s_nv[4];
    const int wid  = threadIdx.x >> 6;
    const int lane = threadIdx.x & 63;
    const int row  = blockIdx.x * 4 + wid;
    const int r    = roi_label[row];

    // dot(inputs[row], lut[clamp(r)]) across the wave (4 elems/lane).
    // Round both sides to bf16 to match the score kernel's quantization.
    float dot = 0.f;
    {
        const int rc = r < 0 ? 0 : r;
        const f32x4 xi = *(const f32x4*)(inputs + (size_t)row * FEAT + lane * 4);
        const f32x4 li = *(const f32x4*)(lut + (size_t)rc * FEAT + lane * 4);
        #pragma unroll
        for (int j = 0; j < 4; ++j) {
            float a = __bfloat162float(__float2bfloat16(xi[j]));
            float b = __bfloat162float(__float2bfloat16(li[j]));
            dot += a * b;
        }
    }
    #pragma unroll
    for (int off = 32; off > 0; off >>= 1) dot += __shfl_xor(dot, off);

    if (lane == 0) {
        const float sbg = sum_bg[row];
        const float snb = sum_nb[row];
        const float inv = 1.f / (sbg + snb);
        const float cls0 = sbg * inv;
        const float cls1 = snb * inv;
        out[2 * row]     = cls0;
        out[2 * row + 1] = cls1;

        // det loss: det_label = (r >= -1) ? 1 : 0
        const float cs = (r >= -1) ? cls1 : cls0;
        const float om = 1.f - cs;
        s_det[wid] = -(0.25f * om * om * logf(cs)) * (1.f / (float)BATCH);
        s_nv[wid]  = (r >= -1) ? 1.f : 0.f;

        float rl = 0.f;
        if (r >= 0) {
            const float slab = 30.f * dot;
            const float logp = slab - logf(snb);   // log_softmax over non-bg
            const float p    = expf(logp);
            const float om2  = 1.f - p;
            rl = -(0.25f * om2 * om2 * logp) * cls1 * cls1;
        }
        s_oim[wid] = rl;
    }
    __syncthreads();
    if (threadIdx.x == 0) {
        atomic_add_f(&accums[0], s_det[0] + s_det[1] + s_det[2] + s_det[3]);
        atomic_add_f(&accums[1], s_oim[0] + s_oim[1] + s_oim[2] + s_oim[3]);
        atomic_add_f(&accums[2], s_nv[0] + s_nv[1] + s_nv[2] + s_nv[3]);
        __threadfence();
        const unsigned t = __hip_atomic_fetch_add(ticket, 1u, __ATOMIC_ACQ_REL,
                                                  __HIP_MEMORY_SCOPE_AGENT);
        if (t == gridDim.x - 1) {   // last block: publish the two scalars
            const float det = __hip_atomic_load(&accums[0], __ATOMIC_RELAXED, __HIP_MEMORY_SCOPE_AGENT);
            const float oim = __hip_atomic_load(&accums[1], __ATOMIC_RELAXED, __HIP_MEMORY_SCOPE_AGENT);
            float nv        = __hip_atomic_load(&accums[2], __ATOMIC_RELAXED, __HIP_MEMORY_SCOPE_AGENT);
            if (nv < 1.f) nv = 1.f;
            out[2 * BATCH]     = det;
            out[2 * BATCH + 1] = oim / nv;
        }
    }
}

extern "C" void kernel_launch(void* const* d_in, const int* in_sizes, int n_in,
                              void* d_out, int out_size, void* d_ws, size_t ws_size,
                              hipStream_t stream)
{
    const float* inputs = (const float*)d_in[0];
    const int*   roi    = (const int*)d_in[1];
    const float* lut    = (const float*)d_in[2];
    const float* cq     = (const float*)d_in[3];
    const float* cqb    = (const float*)d_in[4];
    float* W = (float*)d_ws;
    float* out = (float*)d_out;

    hipMemsetAsync(d_ws, 0, WS_FLOATS * sizeof(float), stream);

    // 61 col-chunks of 256 x 16 row-chunks of 256
    dim3 g1(61, 16);
    score_kernel<<<g1, 256, 0, stream>>>(inputs, lut, cq, cqb, W, W + BATCH);

    finalize_kernel<<<BATCH / 4, 256, 0, stream>>>(
        inputs, roi, lut, W, W + BATCH, W + 2 * BATCH,
        (unsigned int*)(W + 2 * BATCH + 3), out);
}

// Round 6
// 225.492 us; speedup vs baseline: 1.8039x; 1.6437x over previous
//
#include <hip/hip_runtime.h>
#include <hip/hip_bf16.h>

typedef unsigned short u16;
typedef __attribute__((ext_vector_type(8))) short bf16x8;   // 8 bf16 = 4 VGPRs
typedef __attribute__((ext_vector_type(4))) short bf16x4;
typedef __attribute__((ext_vector_type(4))) float f32x4;

#define NBG   5000
#define NPID  5532
#define NTOT  15532      // 5000 + 5532 + 5000
#define FEAT  256
#define BATCH 4096
#define SCALE_LOG2E 43.280851226668994f   // 30 * log2(e)
#define LPITCH 264       // f32-fallback LDS pitch (shorts)

// ---- bf16 workspace layout (bytes) ----
// tab_bf : [0, NTOT*256*2)              = 7,952,384
// a_bf   : [7,952,384, +BATCH*256*2)    -> ends 10,049,536
// sums   : floats at 10,049,536: [0,4096) bg | [4096,8192) nb | det,oim,nv,ticket
#define TAB_BYTES  (NTOT * FEAT * 2)
#define A_BYTES    (BATCH * FEAT * 2)
#define SUMS_OFF   (TAB_BYTES + A_BYTES)
#define SUMS_FLOATS (2 * BATCH + 4)
#define WS_NEED    (SUMS_OFF + SUMS_FLOATS * 4)

__device__ __forceinline__ void atomic_add_f(float* p, float v) {
    __hip_atomic_fetch_add(p, v, __ATOMIC_RELAXED, __HIP_MEMORY_SCOPE_AGENT);
}
__device__ __forceinline__ short f2bf(float f) {
    return (short)__bfloat16_as_ushort(__float2bfloat16(f));
}

__device__ __forceinline__ const float* table_row(
    int n, const float* __restrict__ lut, const float* __restrict__ cq,
    const float* __restrict__ cqb)
{
    const int nc = n < NTOT ? n : NTOT - 1;
    if (nc < NBG)        return cqb + (size_t)nc * FEAT;
    if (nc < NBG + NPID) return lut + (size_t)(nc - NBG) * FEAT;
    return cq + (size_t)(nc - NBG - NPID) * FEAT;
}

// -------- Stage 0: f32 -> bf16 prepass (table + inputs) --------------------
// Each thread converts 8 consecutive elements.
#define TAB_CHUNKS (NTOT * FEAT / 8)      // 497,024
#define A_CHUNKS   (BATCH * FEAT / 8)     // 131,072
#define PRE_CHUNKS (TAB_CHUNKS + A_CHUNKS)

__global__ __launch_bounds__(256) void prepass_kernel(
    const float* __restrict__ inputs, const float* __restrict__ lut,
    const float* __restrict__ cq, const float* __restrict__ cqb,
    u16* __restrict__ tab, u16* __restrict__ abf)
{
    const int i = blockIdx.x * 256 + threadIdx.x;
    if (i >= PRE_CHUNKS) return;
    const float* src;
    u16* dst;
    if (i < TAB_CHUNKS) {
        const int row = i >> 5, c8 = (i & 31) * 8;
        src = table_row(row, lut, cq, cqb) + c8;
        dst = tab + (size_t)row * FEAT + c8;
    } else {
        const int ia = i - TAB_CHUNKS;
        src = inputs + (size_t)ia * 8;
        dst = abf + (size_t)ia * 8;
    }
    const f32x4 lo = *(const f32x4*)src;
    const f32x4 hi = *(const f32x4*)(src + 4);
    bf16x8 r = { f2bf(lo[0]), f2bf(lo[1]), f2bf(lo[2]), f2bf(lo[3]),
                 f2bf(hi[0]), f2bf(hi[1]), f2bf(hi[2]), f2bf(hi[3]) };
    *(bf16x8*)dst = r;
}

// -------- Stage 1 (bf16 path): barrier-free fused GEMM + exp-sum -----------
// 1-D grid of 976 blocks, XCD-swizzled: xcd = lid&7 owns row-chunks {2x,2x+1}
// and sweeps col-chunks in order (sibling row-blocks adjacent -> share B in L2).
// 256 threads = 4 waves; wave owns 64 rows as register A-frags. No LDS at all.
__global__ __launch_bounds__(256, 2) void score_bf16_kernel(
    const u16* __restrict__ tab, const u16* __restrict__ abf,
    float* __restrict__ sum_bg, float* __restrict__ sum_nb)
{
    const int lid = blockIdx.x;
    const int x8  = lid & 7;
    const int j   = lid >> 3;                 // [0, 122)
    const int rowchunk = x8 * 2 + (j & 1);    // [0, 16)
    const int colchunk = j >> 1;              // [0, 61)
    const int rowbase = rowchunk << 8;
    const int colbase = colchunk << 8;

    const int wave = threadIdx.x >> 6;
    const int lane = threadIdx.x & 63;
    const int l15  = lane & 15;
    const int quad = lane >> 4;

    // A fragments: 64 rows (4 sets of 16), direct from global bf16.
    bf16x8 af[4][8];
    {
        const u16* ab = abf + (size_t)(rowbase + wave * 64 + l15) * FEAT + quad * 8;
        #pragma unroll
        for (int s = 0; s < 4; ++s)
            #pragma unroll
            for (int kk = 0; kk < 8; ++kk)
                af[s][kk] = *(const bf16x8*)(ab + (size_t)s * 16 * FEAT + kk * 32);
    }

    float pbg[16], pnb[16];
    #pragma unroll
    for (int i = 0; i < 16; ++i) { pbg[i] = 0.f; pnb[i] = 0.f; }

    #pragma unroll 1
    for (int t = 0; t < 16; ++t) {
        const int n  = colbase + t * 16 + l15;
        const int nc = n < NTOT ? n : NTOT - 1;
        const u16* bb = tab + (size_t)nc * FEAT + quad * 8;

        f32x4 cc[4];
        #pragma unroll
        for (int s = 0; s < 4; ++s) cc[s] = f32x4{0.f, 0.f, 0.f, 0.f};
        #pragma unroll
        for (int kk = 0; kk < 8; ++kk) {
            const bf16x8 b = *(const bf16x8*)(bb + kk * 32);
            cc[0] = __builtin_amdgcn_mfma_f32_16x16x32_bf16(af[0][kk], b, cc[0], 0, 0, 0);
            cc[1] = __builtin_amdgcn_mfma_f32_16x16x32_bf16(af[1][kk], b, cc[1], 0, 0, 0);
            cc[2] = __builtin_amdgcn_mfma_f32_16x16x32_bf16(af[2][kk], b, cc[2], 0, 0, 0);
            cc[3] = __builtin_amdgcn_mfma_f32_16x16x32_bf16(af[3][kk], b, cc[3], 0, 0, 0);
        }

        const bool okc  = n < NTOT;
        const bool isbg = n < NBG;
        #pragma unroll
        for (int s = 0; s < 4; ++s) {
            #pragma unroll
            for (int r = 0; r < 4; ++r) {
                float e = exp2f(cc[s][r] * SCALE_LOG2E);
                e = okc ? e : 0.f;
                pbg[s * 4 + r] += isbg ? e : 0.f;
                pnb[s * 4 + r] += isbg ? 0.f : e;
            }
        }
    }

    #pragma unroll
    for (int off = 1; off < 16; off <<= 1) {
        #pragma unroll
        for (int i = 0; i < 16; ++i) {
            pbg[i] += __shfl_xor(pbg[i], off);
            pnb[i] += __shfl_xor(pnb[i], off);
        }
    }
    if (l15 == 0) {
        #pragma unroll
        for (int s = 0; s < 4; ++s) {
            #pragma unroll
            for (int r = 0; r < 4; ++r) {
                const int row = rowbase + wave * 64 + s * 16 + quad * 4 + r;
                atomic_add_f(&sum_bg[row], pbg[s * 4 + r]);
                atomic_add_f(&sum_nb[row], pnb[s * 4 + r]);
            }
        }
    }
}

// -------- Stage 1 (f32 fallback, round-4 structure) ------------------------
__global__ __launch_bounds__(256, 2) void score_f32_kernel(
    const float* __restrict__ inputs, const float* __restrict__ lut,
    const float* __restrict__ cq, const float* __restrict__ cqb,
    float* __restrict__ sum_bg, float* __restrict__ sum_nb)
{
    __shared__ __align__(16) short lds[32 * LPITCH];
    const int wave = threadIdx.x >> 6;
    const int lane = threadIdx.x & 63;
    const int l15  = lane & 15;
    const int quad = lane >> 4;
    const int rowbase = blockIdx.y * 256;
    const int colbase = blockIdx.x * 256;

    bf16x8 afrag[4][8];
    #pragma unroll 1
    for (int c = 0; c < 8; ++c) {
        __syncthreads();
        #pragma unroll
        for (int i = 0; i < 8; ++i) {
            const int lr = i * 4 + wave;
            const f32x4 v = *(const f32x4*)(inputs + (size_t)(rowbase + c * 32 + lr) * FEAT + lane * 4);
            bf16x4 h = { f2bf(v[0]), f2bf(v[1]), f2bf(v[2]), f2bf(v[3]) };
            *(bf16x4*)(&lds[lr * LPITCH + lane * 4]) = h;
        }
        __syncthreads();
        if ((c >> 1) == wave) {
            const int half = c & 1;
            #pragma unroll
            for (int j2 = 0; j2 < 2; ++j2) {
                const int lr = j2 * 16 + l15;
                #pragma unroll
                for (int kk = 0; kk < 8; ++kk)
                    afrag[half * 2 + j2][kk] =
                        *(const bf16x8*)(&lds[lr * LPITCH + kk * 32 + quad * 8]);
            }
        }
    }

    float pbg[16], pnb[16];
    #pragma unroll
    for (int i = 0; i < 16; ++i) { pbg[i] = 0.f; pnb[i] = 0.f; }

    #pragma unroll 1
    for (int s = 0; s < 8; ++s) {
        __syncthreads();
        #pragma unroll
        for (int i = 0; i < 8; ++i) {
            const int lc = i * 4 + wave;
            const f32x4 v = *(const f32x4*)(table_row(colbase + s * 32 + lc, lut, cq, cqb) + lane * 4);
            bf16x4 h = { f2bf(v[0]), f2bf(v[1]), f2bf(v[2]), f2bf(v[3]) };
            *(bf16x4*)(&lds[lc * LPITCH + lane * 4]) = h;
        }
        __syncthreads();

        #pragma unroll
        for (int st = 0; st < 2; ++st) {
            const int lc = st * 16 + l15;
            f32x4 cc[4];
            #pragma unroll
            for (int q = 0; q < 4; ++q) cc[q] = f32x4{0.f, 0.f, 0.f, 0.f};
            #pragma unroll
            for (int kk = 0; kk < 8; ++kk) {
                const bf16x8 b = *(const bf16x8*)(&lds[lc * LPITCH + kk * 32 + quad * 8]);
                cc[0] = __builtin_amdgcn_mfma_f32_16x16x32_bf16(afrag[0][kk], b, cc[0], 0, 0, 0);
                cc[1] = __builtin_amdgcn_mfma_f32_16x16x32_bf16(afrag[1][kk], b, cc[1], 0, 0, 0);
                cc[2] = __builtin_amdgcn_mfma_f32_16x16x32_bf16(afrag[2][kk], b, cc[2], 0, 0, 0);
                cc[3] = __builtin_amdgcn_mfma_f32_16x16x32_bf16(afrag[3][kk], b, cc[3], 0, 0, 0);
            }
            const int n = colbase + s * 32 + st * 16 + l15;
            const bool okc  = n < NTOT;
            const bool isbg = n < NBG;
            #pragma unroll
            for (int q = 0; q < 4; ++q) {
                #pragma unroll
                for (int r = 0; r < 4; ++r) {
                    float e = exp2f(cc[q][r] * SCALE_LOG2E);
                    e = okc ? e : 0.f;
                    pbg[q * 4 + r] += isbg ? e : 0.f;
                    pnb[q * 4 + r] += isbg ? 0.f : e;
                }
            }
        }
    }

    #pragma unroll
    for (int off = 1; off < 16; off <<= 1) {
        #pragma unroll
        for (int i = 0; i < 16; ++i) {
            pbg[i] += __shfl_xor(pbg[i], off);
            pnb[i] += __shfl_xor(pnb[i], off);
        }
    }
    if (l15 == 0) {
        #pragma unroll
        for (int q = 0; q < 4; ++q) {
            #pragma unroll
            for (int r = 0; r < 4; ++r) {
                const int row = rowbase + wave * 64 + q * 16 + quad * 4 + r;
                atomic_add_f(&sum_bg[row], pbg[q * 4 + r]);
                atomic_add_f(&sum_nb[row], pnb[q * 4 + r]);
            }
        }
    }
}

// -------- Stage 2: per-row finalize + last-block scalar fold ---------------
__global__ __launch_bounds__(256) void finalize_kernel(
    const float* __restrict__ inputs, const int* __restrict__ roi_label,
    const float* __restrict__ lut,
    const float* __restrict__ sum_bg, const float* __restrict__ sum_nb,
    float* __restrict__ accums, unsigned int* __restrict__ ticket,
    float* __restrict__ out)
{
    __shared__ float s_det[4], s_oim[4], s_nv[4];
    const int wid  = threadIdx.x >> 6;
    const int lane = threadIdx.x & 63;
    const int row  = blockIdx.x * 4 + wid;
    const int r    = roi_label[row];

    float dot = 0.f;
    {
        const int rc = r < 0 ? 0 : r;
        const f32x4 xi = *(const f32x4*)(inputs + (size_t)row * FEAT + lane * 4);
        const f32x4 li = *(const f32x4*)(lut + (size_t)rc * FEAT + lane * 4);
        #pragma unroll
        for (int j = 0; j < 4; ++j) {
            float a = __bfloat162float(__float2bfloat16(xi[j]));
            float b = __bfloat162float(__float2bfloat16(li[j]));
            dot += a * b;
        }
    }
    #pragma unroll
    for (int off = 32; off > 0; off >>= 1) dot += __shfl_xor(dot, off);

    if (lane == 0) {
        const float sbg = sum_bg[row];
        const float snb = sum_nb[row];
        const float inv = 1.f / (sbg + snb);
        const float cls0 = sbg * inv;
        const float cls1 = snb * inv;
        out[2 * row]     = cls0;
        out[2 * row + 1] = cls1;

        const float cs = (r >= -1) ? cls1 : cls0;
        const float om = 1.f - cs;
        s_det[wid] = -(0.25f * om * om * logf(cs)) * (1.f / (float)BATCH);
        s_nv[wid]  = (r >= -1) ? 1.f : 0.f;

        float rl = 0.f;
        if (r >= 0) {
            const float slab = 30.f * dot;
            const float logp = slab - logf(snb);
            const float p    = expf(logp);
            const float om2  = 1.f - p;
            rl = -(0.25f * om2 * om2 * logp) * cls1 * cls1;
        }
        s_oim[wid] = rl;
    }
    __syncthreads();
    if (threadIdx.x == 0) {
        atomic_add_f(&accums[0], s_det[0] + s_det[1] + s_det[2] + s_det[3]);
        atomic_add_f(&accums[1], s_oim[0] + s_oim[1] + s_oim[2] + s_oim[3]);
        atomic_add_f(&accums[2], s_nv[0] + s_nv[1] + s_nv[2] + s_nv[3]);
        __threadfence();
        const unsigned t = __hip_atomic_fetch_add(ticket, 1u, __ATOMIC_ACQ_REL,
                                                  __HIP_MEMORY_SCOPE_AGENT);
        if (t == gridDim.x - 1) {
            const float det = __hip_atomic_load(&accums[0], __ATOMIC_RELAXED, __HIP_MEMORY_SCOPE_AGENT);
            const float oim = __hip_atomic_load(&accums[1], __ATOMIC_RELAXED, __HIP_MEMORY_SCOPE_AGENT);
            float nv        = __hip_atomic_load(&accums[2], __ATOMIC_RELAXED, __HIP_MEMORY_SCOPE_AGENT);
            if (nv < 1.f) nv = 1.f;
            out[2 * BATCH]     = det;
            out[2 * BATCH + 1] = oim / nv;
        }
    }
}

extern "C" void kernel_launch(void* const* d_in, const int* in_sizes, int n_in,
                              void* d_out, int out_size, void* d_ws, size_t ws_size,
                              hipStream_t stream)
{
    const float* inputs = (const float*)d_in[0];
    const int*   roi    = (const int*)d_in[1];
    const float* lut    = (const float*)d_in[2];
    const float* cq     = (const float*)d_in[3];
    const float* cqb    = (const float*)d_in[4];
    float* out = (float*)d_out;

    if (ws_size >= (size_t)WS_NEED) {
        u16* tab = (u16*)d_ws;
        u16* abf = (u16*)((char*)d_ws + TAB_BYTES);
        float* S = (float*)((char*)d_ws + SUMS_OFF);
        hipMemsetAsync(S, 0, SUMS_FLOATS * sizeof(float), stream);
        prepass_kernel<<<(PRE_CHUNKS + 255) / 256, 256, 0, stream>>>(
            inputs, lut, cq, cqb, tab, abf);
        score_bf16_kernel<<<976, 256, 0, stream>>>(tab, abf, S, S + BATCH);
        finalize_kernel<<<BATCH / 4, 256, 0, stream>>>(
            inputs, roi, lut, S, S + BATCH, S + 2 * BATCH,
            (unsigned int*)(S + 2 * BATCH + 3), out);
    } else {
        float* S = (float*)d_ws;
        hipMemsetAsync(S, 0, SUMS_FLOATS * sizeof(float), stream);
        dim3 g1(61, 16);
        score_f32_kernel<<<g1, 256, 0, stream>>>(inputs, lut, cq, cqb, S, S + BATCH);
        finalize_kernel<<<BATCH / 4, 256, 0, stream>>>(
            inputs, roi, lut, S, S + BATCH, S + 2 * BATCH,
            (unsigned int*)(S + 2 * BATCH + 3), out);
    }
}

// Round 8
// 150.665 us; speedup vs baseline: 2.6999x; 1.4966x over previous
//
#include <hip/hip_runtime.h>
#include <hip/hip_bf16.h>

typedef unsigned short u16;
typedef __attribute__((ext_vector_type(8))) short bf16x8;   // 8 bf16 = 4 VGPRs
typedef __attribute__((ext_vector_type(4))) short bf16x4;
typedef __attribute__((ext_vector_type(4))) float f32x4;

#define NBG   5000
#define NPID  5532
#define NTOT  15532      // 5000 + 5532 + 5000
#define FEAT  256
#define BATCH 4096
#define SCALE_LOG2E 43.280851226668994f   // 30 * log2(e)
#define LPITCH 264       // f32-fallback LDS pitch (shorts)

#define NTILE_B  976             // 61 chunks x 16 tiles; 971 real, 5 zero-pad
#define TILE_SH  4096            // shorts per 16-col tile (16*256)
#define NTILE_A  256             // 4096 rows / 16

// ---- workspace layout (bytes) ----
#define TABT_BYTES ((size_t)NTILE_B * TILE_SH * 2)   // 7,995,392
#define AT_BYTES   ((size_t)NTILE_A * TILE_SH * 2)   // 2,097,152
#define SUMS_OFF   (TABT_BYTES + AT_BYTES)
// S floats: [0,4096) bg | [4096,8192) nb | 8192 det | 8193 oim | 8194 nv | 8195 ticket
#define SUMS_FLOATS 8196
#define WS_NEED    (SUMS_OFF + SUMS_FLOATS * 4)

__device__ __forceinline__ void atomic_add_f(float* p, float v) {
    __hip_atomic_fetch_add(p, v, __ATOMIC_RELAXED, __HIP_MEMORY_SCOPE_AGENT);
}
__device__ __forceinline__ short f2bf(float f) {
    return (short)__bfloat16_as_ushort(__float2bfloat16(f));
}

__device__ __forceinline__ const float* table_row(
    int n, const float* __restrict__ lut, const float* __restrict__ cq,
    const float* __restrict__ cqb)
{
    const int nc = n < NTOT ? n : NTOT - 1;
    if (nc < NBG)        return cqb + (size_t)nc * FEAT;
    if (nc < NBG + NPID) return lut + (size_t)(nc - NBG) * FEAT;
    return cq + (size_t)(nc - NBG - NPID) * FEAT;
}

// -------- Stage 0: f32 -> bf16 tiled prepass (table + inputs) + zero sums --
// Tile format (8192 B per 16-col tile): short off = kk*512 + col*32 + q*8
// holding src[col][kk*32 + q*8 .. +8] -> a wave's MFMA B/A-frag read of
// (kk, all 16 cols, quad) is byte off kk*1024 + lane-unique*16: coalesced.
#define TAB_UNITS (NTILE_B * 512)    // 499,712
#define A_UNITS   (NTILE_A * 512)    // 131,072
#define PRE_BLOCKS ((TAB_UNITS + A_UNITS) / 256)   // 2464

__global__ __launch_bounds__(256) void prepass_kernel(
    const float* __restrict__ inputs, const float* __restrict__ lut,
    const float* __restrict__ cq, const float* __restrict__ cqb,
    u16* __restrict__ tabt, u16* __restrict__ at, float* __restrict__ S)
{
    const int u = blockIdx.x * 256 + threadIdx.x;
    if (u < SUMS_FLOATS) S[u] = 0.f;

    if (u < TAB_UNITS) {
        const int tile = u >> 9, v = u & 511;
        const int kk = v >> 6, col = (v >> 2) & 15, q = v & 3;
        const int cg = tile * 16 + col;
        bf16x8 r = {0, 0, 0, 0, 0, 0, 0, 0};
        if (cg < NTOT) {
            const float* src = table_row(cg, lut, cq, cqb) + kk * 32 + q * 8;
            const f32x4 lo = *(const f32x4*)src;
            const f32x4 hi = *(const f32x4*)(src + 4);
            r = bf16x8{ f2bf(lo[0]), f2bf(lo[1]), f2bf(lo[2]), f2bf(lo[3]),
                        f2bf(hi[0]), f2bf(hi[1]), f2bf(hi[2]), f2bf(hi[3]) };
        }
        *(bf16x8*)(tabt + (size_t)u * 8) = r;
    } else {
        const int ua = u - TAB_UNITS;
        const int tile = ua >> 9, v = ua & 511;
        const int kk = v >> 6, row = (v >> 2) & 15, q = v & 3;
        const float* src = inputs + (size_t)(tile * 16 + row) * FEAT + kk * 32 + q * 8;
        const f32x4 lo = *(const f32x4*)src;
        const f32x4 hi = *(const f32x4*)(src + 4);
        bf16x8 r = { f2bf(lo[0]), f2bf(lo[1]), f2bf(lo[2]), f2bf(lo[3]),
                     f2bf(hi[0]), f2bf(hi[1]), f2bf(hi[2]), f2bf(hi[3]) };
        *(bf16x8*)(at + (size_t)ua * 8) = r;
    }
}

// -------- Stage 1: fused GEMM + exp-sum. No LDS, no barriers. --------------
// 976 blocks (16 rowchunks x 61 colchunks), XCD-swizzled. 4 waves; wave owns
// 4 row-tiles (64 rows). All A/B fragment reads are coalesced (tiled layout).
__global__ __launch_bounds__(256, 2) void score_bf16_kernel(
    const u16* __restrict__ tabt, const u16* __restrict__ at,
    float* __restrict__ sum_bg, float* __restrict__ sum_nb)
{
    const int lid = blockIdx.x;
    const int x8  = lid & 7;
    const int j   = lid >> 3;                 // [0, 122)
    const int rowchunk = x8 * 2 + (j & 1);    // [0, 16)
    const int colchunk = j >> 1;              // [0, 61)

    const int wave = threadIdx.x >> 6;
    const int lane = threadIdx.x & 63;
    const int l15  = lane & 15;
    const int quad = lane >> 4;

    // A fragments: 4 row-tiles, coalesced 1 KB/wave reads.
    bf16x8 af[4][8];
    {
        const u16* ab = at + (size_t)(rowchunk * 16 + wave * 4) * TILE_SH
                           + l15 * 32 + quad * 8;
        #pragma unroll
        for (int s = 0; s < 4; ++s)
            #pragma unroll
            for (int kk = 0; kk < 8; ++kk)
                af[s][kk] = *(const bf16x8*)(ab + (size_t)s * TILE_SH + kk * 512);
    }

    float pbg[16], pnb[16];
    #pragma unroll
    for (int i = 0; i < 16; ++i) { pbg[i] = 0.f; pnb[i] = 0.f; }

    const int bt0  = colchunk * 16;
    const int tmax = (colchunk == 60) ? 11 : 16;   // tiles 971..975 are all-pad

    #pragma unroll 1
    for (int t = 0; t < tmax; ++t) {
        const int bt = bt0 + t;                // global 16-col tile index
        const u16* bb = tabt + (size_t)bt * TILE_SH + l15 * 32 + quad * 8;

        f32x4 cc[4];
        #pragma unroll
        for (int s = 0; s < 4; ++s) cc[s] = f32x4{0.f, 0.f, 0.f, 0.f};
        #pragma unroll
        for (int kk = 0; kk < 8; ++kk) {
            const bf16x8 b = *(const bf16x8*)(bb + kk * 512);
            cc[0] = __builtin_amdgcn_mfma_f32_16x16x32_bf16(af[0][kk], b, cc[0], 0, 0, 0);
            cc[1] = __builtin_amdgcn_mfma_f32_16x16x32_bf16(af[1][kk], b, cc[1], 0, 0, 0);
            cc[2] = __builtin_amdgcn_mfma_f32_16x16x32_bf16(af[2][kk], b, cc[2], 0, 0, 0);
            cc[3] = __builtin_amdgcn_mfma_f32_16x16x32_bf16(af[3][kk], b, cc[3], 0, 0, 0);
        }

        if (colchunk != 60) {
            if (bt < 312) {                    // all background
                #pragma unroll
                for (int s = 0; s < 4; ++s)
                    #pragma unroll
                    for (int r = 0; r < 4; ++r)
                        pbg[s * 4 + r] += exp2f(cc[s][r] * SCALE_LOG2E);
            } else if (bt > 312) {             // all non-bg
                #pragma unroll
                for (int s = 0; s < 4; ++s)
                    #pragma unroll
                    for (int r = 0; r < 4; ++r)
                        pnb[s * 4 + r] += exp2f(cc[s][r] * SCALE_LOG2E);
            } else {                           // tile 312: cols 4992..5007
                const bool isbg = l15 < 8;
                #pragma unroll
                for (int s = 0; s < 4; ++s)
                    #pragma unroll
                    for (int r = 0; r < 4; ++r) {
                        const float e = exp2f(cc[s][r] * SCALE_LOG2E);
                        pbg[s * 4 + r] += isbg ? e : 0.f;
                        pnb[s * 4 + r] += isbg ? 0.f : e;
                    }
            }
        } else {                               // last chunk: mask pad cols
            const bool okc = (bt * 16 + l15) < NTOT;
            #pragma unroll
            for (int s = 0; s < 4; ++s)
                #pragma unroll
                for (int r = 0; r < 4; ++r) {
                    const float e = exp2f(cc[s][r] * SCALE_LOG2E);
                    pnb[s * 4 + r] += okc ? e : 0.f;
                }
        }
    }

    #pragma unroll
    for (int off = 1; off < 16; off <<= 1) {
        #pragma unroll
        for (int i = 0; i < 16; ++i) {
            pbg[i] += __shfl_xor(pbg[i], off);
            pnb[i] += __shfl_xor(pnb[i], off);
        }
    }
    if (l15 == 0) {
        #pragma unroll
        for (int s = 0; s < 4; ++s) {
            #pragma unroll
            for (int r = 0; r < 4; ++r) {
                const int row = (rowchunk * 16 + wave * 4 + s) * 16 + quad * 4 + r;
                atomic_add_f(&sum_bg[row], pbg[s * 4 + r]);
                atomic_add_f(&sum_nb[row], pnb[s * 4 + r]);
            }
        }
    }
}

// -------- Stage 1 (f32 fallback, round-4 structure, proven) ----------------
__global__ __launch_bounds__(256, 2) void score_f32_kernel(
    const float* __restrict__ inputs, const float* __restrict__ lut,
    const float* __restrict__ cq, const float* __restrict__ cqb,
    float* __restrict__ sum_bg, float* __restrict__ sum_nb)
{
    __shared__ __align__(16) short lds[32 * LPITCH];
    const int wave = threadIdx.x >> 6;
    const int lane = threadIdx.x & 63;
    const int l15  = lane & 15;
    const int quad = lane >> 4;
    const int rowbase = blockIdx.y * 256;
    const int colbase = blockIdx.x * 256;

    bf16x8 afrag[4][8];
    #pragma unroll 1
    for (int c = 0; c < 8; ++c) {
        __syncthreads();
        #pragma unroll
        for (int i = 0; i < 8; ++i) {
            const int lr = i * 4 + wave;
            const f32x4 v = *(const f32x4*)(inputs + (size_t)(rowbase + c * 32 + lr) * FEAT + lane * 4);
            bf16x4 h = { f2bf(v[0]), f2bf(v[1]), f2bf(v[2]), f2bf(v[3]) };
            *(bf16x4*)(&lds[lr * LPITCH + lane * 4]) = h;
        }
        __syncthreads();
        if ((c >> 1) == wave) {
            const int half = c & 1;
            #pragma unroll
            for (int j2 = 0; j2 < 2; ++j2) {
                const int lr = j2 * 16 + l15;
                #pragma unroll
                for (int kk = 0; kk < 8; ++kk)
                    afrag[half * 2 + j2][kk] =
                        *(const bf16x8*)(&lds[lr * LPITCH + kk * 32 + quad * 8]);
            }
        }
    }

    float pbg[16], pnb[16];
    #pragma unroll
    for (int i = 0; i < 16; ++i) { pbg[i] = 0.f; pnb[i] = 0.f; }

    #pragma unroll 1
    for (int s = 0; s < 8; ++s) {
        __syncthreads();
        #pragma unroll
        for (int i = 0; i < 8; ++i) {
            const int lc = i * 4 + wave;
            const f32x4 v = *(const f32x4*)(table_row(colbase + s * 32 + lc, lut, cq, cqb) + lane * 4);
            bf16x4 h = { f2bf(v[0]), f2bf(v[1]), f2bf(v[2]), f2bf(v[3]) };
            *(bf16x4*)(&lds[lc * LPITCH + lane * 4]) = h;
        }
        __syncthreads();

        #pragma unroll
        for (int st = 0; st < 2; ++st) {
            const int lc = st * 16 + l15;
            f32x4 cc[4];
            #pragma unroll
            for (int q = 0; q < 4; ++q) cc[q] = f32x4{0.f, 0.f, 0.f, 0.f};
            #pragma unroll
            for (int kk = 0; kk < 8; ++kk) {
                const bf16x8 b = *(const bf16x8*)(&lds[lc * LPITCH + kk * 32 + quad * 8]);
                cc[0] = __builtin_amdgcn_mfma_f32_16x16x32_bf16(afrag[0][kk], b, cc[0], 0, 0, 0);
                cc[1] = __builtin_amdgcn_mfma_f32_16x16x32_bf16(afrag[1][kk], b, cc[1], 0, 0, 0);
                cc[2] = __builtin_amdgcn_mfma_f32_16x16x32_bf16(afrag[2][kk], b, cc[2], 0, 0, 0);
                cc[3] = __builtin_amdgcn_mfma_f32_16x16x32_bf16(afrag[3][kk], b, cc[3], 0, 0, 0);
            }
            const int n = colbase + s * 32 + st * 16 + l15;
            const bool okc  = n < NTOT;
            const bool isbg = n < NBG;
            #pragma unroll
            for (int q = 0; q < 4; ++q) {
                #pragma unroll
                for (int r = 0; r < 4; ++r) {
                    float e = exp2f(cc[q][r] * SCALE_LOG2E);
                    e = okc ? e : 0.f;
                    pbg[q * 4 + r] += isbg ? e : 0.f;
                    pnb[q * 4 + r] += isbg ? 0.f : e;
                }
            }
        }
    }

    #pragma unroll
    for (int off = 1; off < 16; off <<= 1) {
        #pragma unroll
        for (int i = 0; i < 16; ++i) {
            pbg[i] += __shfl_xor(pbg[i], off);
            pnb[i] += __shfl_xor(pnb[i], off);
        }
    }
    if (l15 == 0) {
        #pragma unroll
        for (int q = 0; q < 4; ++q) {
            #pragma unroll
            for (int r = 0; r < 4; ++r) {
                const int row = rowbase + wave * 64 + q * 16 + quad * 4 + r;
                atomic_add_f(&sum_bg[row], pbg[q * 4 + r]);
                atomic_add_f(&sum_nb[row], pnb[q * 4 + r]);
            }
        }
    }
}

// -------- Stage 2: finalize (128 blocks; wave = 8 rows) + scalar fold ------
__global__ __launch_bounds__(256) void finalize_kernel(
    const float* __restrict__ inputs, const int* __restrict__ roi_label,
    const float* __restrict__ lut,
    const float* __restrict__ sum_bg, const float* __restrict__ sum_nb,
    float* __restrict__ accums, unsigned int* __restrict__ ticket,
    float* __restrict__ out)
{
    __shared__ float s_det[4], s_oim[4], s_nv[4];
    const int wid  = threadIdx.x >> 6;
    const int lane = threadIdx.x & 63;

    float det_a = 0.f, oim_a = 0.f, nv_a = 0.f;

    #pragma unroll 1
    for (int it = 0; it < 8; ++it) {
        const int row = blockIdx.x * 32 + wid * 8 + it;
        const int r   = roi_label[row];

        float dot = 0.f;
        {
            const int rc = r < 0 ? 0 : r;
            const f32x4 xi = *(const f32x4*)(inputs + (size_t)row * FEAT + lane * 4);
            const f32x4 li = *(const f32x4*)(lut + (size_t)rc * FEAT + lane * 4);
            #pragma unroll
            for (int jj = 0; jj < 4; ++jj) {
                float a = __bfloat162float(__float2bfloat16(xi[jj]));
                float b = __bfloat162float(__float2bfloat16(li[jj]));
                dot += a * b;
            }
        }
        #pragma unroll
        for (int off = 32; off > 0; off >>= 1) dot += __shfl_xor(dot, off);

        if (lane == 0) {
            const float sbg = sum_bg[row];
            const float snb = sum_nb[row];
            const float inv = 1.f / (sbg + snb);
            const float cls0 = sbg * inv;
            const float cls1 = snb * inv;
            out[2 * row]     = cls0;
            out[2 * row + 1] = cls1;

            const float cs = (r >= -1) ? cls1 : cls0;
            const float om = 1.f - cs;
            det_a += -(0.25f * om * om * logf(cs)) * (1.f / (float)BATCH);
            nv_a  += (r >= -1) ? 1.f : 0.f;

            if (r >= 0) {
                const float slab = 30.f * dot;
                const float logp = slab - logf(snb);
                const float p    = expf(logp);
                const float om2  = 1.f - p;
                oim_a += -(0.25f * om2 * om2 * logp) * cls1 * cls1;
            }
        }
    }

    if (lane == 0) { s_det[wid] = det_a; s_oim[wid] = oim_a; s_nv[wid] = nv_a; }
    __syncthreads();
    if (threadIdx.x == 0) {
        atomic_add_f(&accums[0], s_det[0] + s_det[1] + s_det[2] + s_det[3]);
        atomic_add_f(&accums[1], s_oim[0] + s_oim[1] + s_oim[2] + s_oim[3]);
        atomic_add_f(&accums[2], s_nv[0] + s_nv[1] + s_nv[2] + s_nv[3]);
        __threadfence();
        const unsigned t = __hip_atomic_fetch_add(ticket, 1u, __ATOMIC_ACQ_REL,
                                                  __HIP_MEMORY_SCOPE_AGENT);
        if (t == gridDim.x - 1) {
            const float det = __hip_atomic_load(&accums[0], __ATOMIC_RELAXED, __HIP_MEMORY_SCOPE_AGENT);
            const float oim = __hip_atomic_load(&accums[1], __ATOMIC_RELAXED, __HIP_MEMORY_SCOPE_AGENT);
            float nv        = __hip_atomic_load(&accums[2], __ATOMIC_RELAXED, __HIP_MEMORY_SCOPE_AGENT);
            if (nv < 1.f) nv = 1.f;
            out[2 * BATCH]     = det;
            out[2 * BATCH + 1] = oim / nv;
        }
    }
}

extern "C" void kernel_launch(void* const* d_in, const int* in_sizes, int n_in,
                              void* d_out, int out_size, void* d_ws, size_t ws_size,
                              hipStream_t stream)
{
    const float* inputs = (const float*)d_in[0];
    const int*   roi    = (const int*)d_in[1];
    const float* lut    = (const float*)d_in[2];
    const float* cq     = (const float*)d_in[3];
    const float* cqb    = (const float*)d_in[4];
    float* out = (float*)d_out;

    if (ws_size >= (size_t)WS_NEED) {
        u16* tabt = (u16*)d_ws;
        u16* at   = (u16*)((char*)d_ws + TABT_BYTES);
        float* S  = (float*)((char*)d_ws + SUMS_OFF);
        prepass_kernel<<<PRE_BLOCKS, 256, 0, stream>>>(inputs, lut, cq, cqb, tabt, at, S);
        score_bf16_kernel<<<976, 256, 0, stream>>>(tabt, at, S, S + BATCH);
        finalize_kernel<<<128, 256, 0, stream>>>(
            inputs, roi, lut, S, S + BATCH, S + 2 * BATCH,
            (unsigned int*)(S + 2 * BATCH + 3), out);
    } else {
        float* S = (float*)d_ws;
        hipMemsetAsync(S, 0, SUMS_FLOATS * sizeof(float), stream);
        dim3 g1(61, 16);
        score_f32_kernel<<<g1, 256, 0, stream>>>(inputs, lut, cq, cqb, S, S + BATCH);
        finalize_kernel<<<128, 256, 0, stream>>>(
            inputs, roi, lut, S, S + BATCH, S + 2 * BATCH,
            (unsigned int*)(S + 2 * BATCH + 3), out);
    }
}

// Round 9
// 139.864 us; speedup vs baseline: 2.9083x; 1.0772x over previous
//
#include <hip/hip_runtime.h>
#include <hip/hip_bf16.h>

typedef unsigned short u16;
typedef __attribute__((ext_vector_type(8))) short bf16x8;   // 8 bf16 = 4 VGPRs
typedef __attribute__((ext_vector_type(4))) short bf16x4;
typedef __attribute__((ext_vector_type(4))) float f32x4;

#define NBG   5000
#define NPID  5532
#define NTOT  15532      // 5000 + 5532 + 5000
#define FEAT  256
#define BATCH 4096
#define SCALE_LOG2E 43.280851226668994f   // 30 * log2(e)
#define LPITCH 264       // f32-fallback LDS pitch (shorts)

#define NTILE_B  976             // 61 chunks x 16 tiles; 971 real, 5 zero-pad
#define TILE_SH  4096            // shorts per 16-col tile (16*256)
#define NTILE_A  256             // 4096 rows / 16

// ---- workspace layout (bytes) ----
#define TABT_BYTES ((size_t)NTILE_B * TILE_SH * 2)   // 7,995,392
#define AT_BYTES   ((size_t)NTILE_A * TILE_SH * 2)   // 2,097,152
#define SUMS_OFF   (TABT_BYTES + AT_BYTES)
// S floats: [0,4096) bg | [4096,8192) nb | 8192 det | 8193 oim | 8194 nv | 8195 ticket
#define SUMS_FLOATS 8196
#define WS_NEED    (SUMS_OFF + SUMS_FLOATS * 4)

__device__ __forceinline__ void atomic_add_f(float* p, float v) {
    __hip_atomic_fetch_add(p, v, __ATOMIC_RELAXED, __HIP_MEMORY_SCOPE_AGENT);
}
__device__ __forceinline__ short f2bf(float f) {
    return (short)__bfloat16_as_ushort(__float2bfloat16(f));
}

__device__ __forceinline__ const float* table_row(
    int n, const float* __restrict__ lut, const float* __restrict__ cq,
    const float* __restrict__ cqb)
{
    const int nc = n < NTOT ? n : NTOT - 1;
    if (nc < NBG)        return cqb + (size_t)nc * FEAT;
    if (nc < NBG + NPID) return lut + (size_t)(nc - NBG) * FEAT;
    return cq + (size_t)(nc - NBG - NPID) * FEAT;
}

// -------- Stage 0: f32 -> bf16 tiled prepass (table + inputs) + zero sums --
// Tile format (8192 B per 16-col tile): short off = kk*512 + col*32 + q*8
// holding src[col][kk*32 + q*8 .. +8] -> a wave's MFMA B/A-frag read of
// (kk, all 16 cols, quad) is byte off kk*1024 + lane-unique*16: coalesced.
#define TAB_UNITS (NTILE_B * 512)    // 499,712
#define A_UNITS   (NTILE_A * 512)    // 131,072
#define PRE_BLOCKS ((TAB_UNITS + A_UNITS) / 256)   // 2464

__global__ __launch_bounds__(256) void prepass_kernel(
    const float* __restrict__ inputs, const float* __restrict__ lut,
    const float* __restrict__ cq, const float* __restrict__ cqb,
    u16* __restrict__ tabt, u16* __restrict__ at, float* __restrict__ S)
{
    const int u = blockIdx.x * 256 + threadIdx.x;
    if (u < SUMS_FLOATS) S[u] = 0.f;

    if (u < TAB_UNITS) {
        const int tile = u >> 9, v = u & 511;
        const int kk = v >> 6, col = (v >> 2) & 15, q = v & 3;
        const int cg = tile * 16 + col;
        bf16x8 r = {0, 0, 0, 0, 0, 0, 0, 0};
        if (cg < NTOT) {
            const float* src = table_row(cg, lut, cq, cqb) + kk * 32 + q * 8;
            const f32x4 lo = *(const f32x4*)src;
            const f32x4 hi = *(const f32x4*)(src + 4);
            r = bf16x8{ f2bf(lo[0]), f2bf(lo[1]), f2bf(lo[2]), f2bf(lo[3]),
                        f2bf(hi[0]), f2bf(hi[1]), f2bf(hi[2]), f2bf(hi[3]) };
        }
        *(bf16x8*)(tabt + (size_t)u * 8) = r;
    } else {
        const int ua = u - TAB_UNITS;
        const int tile = ua >> 9, v = ua & 511;
        const int kk = v >> 6, row = (v >> 2) & 15, q = v & 3;
        const float* src = inputs + (size_t)(tile * 16 + row) * FEAT + kk * 32 + q * 8;
        const f32x4 lo = *(const f32x4*)src;
        const f32x4 hi = *(const f32x4*)(src + 4);
        bf16x8 r = { f2bf(lo[0]), f2bf(lo[1]), f2bf(lo[2]), f2bf(lo[3]),
                     f2bf(hi[0]), f2bf(hi[1]), f2bf(hi[2]), f2bf(hi[3]) };
        *(bf16x8*)(at + (size_t)ua * 8) = r;
    }
}

// -------- Stage 1: fused GEMM + exp-sum, LDS-shared B ----------------------
// 976 blocks (16 rowchunks x 61 colchunks), XCD-swizzled. 4 waves; wave owns
// 4 row-tiles (64 rows) in register A-frags. Each 8 KB B-tile is staged into
// LDS ONCE per block (was once per wave -> 4x the L1 line traffic), via
// regs + ds_write (compiler-tracked; no global_load_lds race). Double-buffer,
// ONE barrier/tile: write(t) targets the buffer last read at consume(t-2),
// which completed before barrier(t-1) -> no hazard.
__global__ __launch_bounds__(256, 2) void score_bf16_kernel(
    const u16* __restrict__ tabt, const u16* __restrict__ at,
    float* __restrict__ sum_bg, float* __restrict__ sum_nb)
{
    __shared__ __align__(16) short lbuf[2][TILE_SH];
    const int lid = blockIdx.x;
    const int x8  = lid & 7;
    const int j   = lid >> 3;                 // [0, 122)
    const int rowchunk = x8 * 2 + (j & 1);    // [0, 16)
    const int colchunk = j >> 1;              // [0, 61)

    const int tid  = threadIdx.x;
    const int wave = tid >> 6;
    const int lane = tid & 63;
    const int l15  = lane & 15;
    const int quad = lane >> 4;

    // A fragments: 4 row-tiles, coalesced 1 KB/wave reads.
    bf16x8 af[4][8];
    {
        const u16* ab = at + (size_t)(rowchunk * 16 + wave * 4) * TILE_SH
                           + l15 * 32 + quad * 8;
        #pragma unroll
        for (int s = 0; s < 4; ++s)
            #pragma unroll
            for (int kk = 0; kk < 8; ++kk)
                af[s][kk] = *(const bf16x8*)(ab + (size_t)s * TILE_SH + kk * 512);
    }

    float pbg[16], pnb[16];
    #pragma unroll
    for (int i = 0; i < 16; ++i) { pbg[i] = 0.f; pnb[i] = 0.f; }

    const int bt0  = colchunk * 16;
    const int tmax = (colchunk == 60) ? 11 : 16;   // tiles 971..975 are all-pad

    // preload tile 0 staging regs (each thread 32 B, two contiguous 4 KB halves)
    bf16x8 r0, r1;
    {
        const u16* g = tabt + (size_t)bt0 * TILE_SH;
        r0 = *(const bf16x8*)(g + tid * 8);
        r1 = *(const bf16x8*)(g + 2048 + tid * 8);
    }

    #pragma unroll 1
    for (int t = 0; t < tmax; ++t) {
        const int bt = bt0 + t;                // global 16-col tile index
        {
            short* dst = lbuf[t & 1];
            *(bf16x8*)(dst + tid * 8) = r0;
            *(bf16x8*)(dst + 2048 + tid * 8) = r1;
        }
        if (t + 1 < tmax) {                    // prefetch next tile into regs
            const u16* g = tabt + (size_t)(bt + 1) * TILE_SH;
            r0 = *(const bf16x8*)(g + tid * 8);
            r1 = *(const bf16x8*)(g + 2048 + tid * 8);
        }
        __syncthreads();                       // tile t visible to all waves

        const short* lb = lbuf[t & 1];
        f32x4 cc[4];
        #pragma unroll
        for (int s = 0; s < 4; ++s) cc[s] = f32x4{0.f, 0.f, 0.f, 0.f};
        #pragma unroll
        for (int kk = 0; kk < 8; ++kk) {
            const bf16x8 b = *(const bf16x8*)(lb + kk * 512 + l15 * 32 + quad * 8);
            cc[0] = __builtin_amdgcn_mfma_f32_16x16x32_bf16(af[0][kk], b, cc[0], 0, 0, 0);
            cc[1] = __builtin_amdgcn_mfma_f32_16x16x32_bf16(af[1][kk], b, cc[1], 0, 0, 0);
            cc[2] = __builtin_amdgcn_mfma_f32_16x16x32_bf16(af[2][kk], b, cc[2], 0, 0, 0);
            cc[3] = __builtin_amdgcn_mfma_f32_16x16x32_bf16(af[3][kk], b, cc[3], 0, 0, 0);
        }

        if (colchunk != 60) {
            if (bt < 312) {                    // all background
                #pragma unroll
                for (int s = 0; s < 4; ++s)
                    #pragma unroll
                    for (int r = 0; r < 4; ++r)
                        pbg[s * 4 + r] += exp2f(cc[s][r] * SCALE_LOG2E);
            } else if (bt > 312) {             // all non-bg
                #pragma unroll
                for (int s = 0; s < 4; ++s)
                    #pragma unroll
                    for (int r = 0; r < 4; ++r)
                        pnb[s * 4 + r] += exp2f(cc[s][r] * SCALE_LOG2E);
            } else {                           // tile 312: cols 4992..5007
                const bool isbg = l15 < 8;
                #pragma unroll
                for (int s = 0; s < 4; ++s)
                    #pragma unroll
                    for (int r = 0; r < 4; ++r) {
                        const float e = exp2f(cc[s][r] * SCALE_LOG2E);
                        pbg[s * 4 + r] += isbg ? e : 0.f;
                        pnb[s * 4 + r] += isbg ? 0.f : e;
                    }
            }
        } else {                               // last chunk: mask pad cols
            const bool okc = (bt * 16 + l15) < NTOT;
            #pragma unroll
            for (int s = 0; s < 4; ++s)
                #pragma unroll
                for (int r = 0; r < 4; ++r) {
                    const float e = exp2f(cc[s][r] * SCALE_LOG2E);
                    pnb[s * 4 + r] += okc ? e : 0.f;
                }
        }
    }

    #pragma unroll
    for (int off = 1; off < 16; off <<= 1) {
        #pragma unroll
        for (int i = 0; i < 16; ++i) {
            pbg[i] += __shfl_xor(pbg[i], off);
            pnb[i] += __shfl_xor(pnb[i], off);
        }
    }
    if (l15 == 0) {
        #pragma unroll
        for (int s = 0; s < 4; ++s) {
            #pragma unroll
            for (int r = 0; r < 4; ++r) {
                const int row = (rowchunk * 16 + wave * 4 + s) * 16 + quad * 4 + r;
                atomic_add_f(&sum_bg[row], pbg[s * 4 + r]);
                atomic_add_f(&sum_nb[row], pnb[s * 4 + r]);
            }
        }
    }
}

// -------- Stage 1 (f32 fallback, round-4 structure, proven) ----------------
__global__ __launch_bounds__(256, 2) void score_f32_kernel(
    const float* __restrict__ inputs, const float* __restrict__ lut,
    const float* __restrict__ cq, const float* __restrict__ cqb,
    float* __restrict__ sum_bg, float* __restrict__ sum_nb)
{
    __shared__ __align__(16) short lds[32 * LPITCH];
    const int wave = threadIdx.x >> 6;
    const int lane = threadIdx.x & 63;
    const int l15  = lane & 15;
    const int quad = lane >> 4;
    const int rowbase = blockIdx.y * 256;
    const int colbase = blockIdx.x * 256;

    bf16x8 afrag[4][8];
    #pragma unroll 1
    for (int c = 0; c < 8; ++c) {
        __syncthreads();
        #pragma unroll
        for (int i = 0; i < 8; ++i) {
            const int lr = i * 4 + wave;
            const f32x4 v = *(const f32x4*)(inputs + (size_t)(rowbase + c * 32 + lr) * FEAT + lane * 4);
            bf16x4 h = { f2bf(v[0]), f2bf(v[1]), f2bf(v[2]), f2bf(v[3]) };
            *(bf16x4*)(&lds[lr * LPITCH + lane * 4]) = h;
        }
        __syncthreads();
        if ((c >> 1) == wave) {
            const int half = c & 1;
            #pragma unroll
            for (int j2 = 0; j2 < 2; ++j2) {
                const int lr = j2 * 16 + l15;
                #pragma unroll
                for (int kk = 0; kk < 8; ++kk)
                    afrag[half * 2 + j2][kk] =
                        *(const bf16x8*)(&lds[lr * LPITCH + kk * 32 + quad * 8]);
            }
        }
    }

    float pbg[16], pnb[16];
    #pragma unroll
    for (int i = 0; i < 16; ++i) { pbg[i] = 0.f; pnb[i] = 0.f; }

    #pragma unroll 1
    for (int s = 0; s < 8; ++s) {
        __syncthreads();
        #pragma unroll
        for (int i = 0; i < 8; ++i) {
            const int lc = i * 4 + wave;
            const f32x4 v = *(const f32x4*)(table_row(colbase + s * 32 + lc, lut, cq, cqb) + lane * 4);
            bf16x4 h = { f2bf(v[0]), f2bf(v[1]), f2bf(v[2]), f2bf(v[3]) };
            *(bf16x4*)(&lds[lc * LPITCH + lane * 4]) = h;
        }
        __syncthreads();

        #pragma unroll
        for (int st = 0; st < 2; ++st) {
            const int lc = st * 16 + l15;
            f32x4 cc[4];
            #pragma unroll
            for (int q = 0; q < 4; ++q) cc[q] = f32x4{0.f, 0.f, 0.f, 0.f};
            #pragma unroll
            for (int kk = 0; kk < 8; ++kk) {
                const bf16x8 b = *(const bf16x8*)(&lds[lc * LPITCH + kk * 32 + quad * 8]);
                cc[0] = __builtin_amdgcn_mfma_f32_16x16x32_bf16(afrag[0][kk], b, cc[0], 0, 0, 0);
                cc[1] = __builtin_amdgcn_mfma_f32_16x16x32_bf16(afrag[1][kk], b, cc[1], 0, 0, 0);
                cc[2] = __builtin_amdgcn_mfma_f32_16x16x32_bf16(afrag[2][kk], b, cc[2], 0, 0, 0);
                cc[3] = __builtin_amdgcn_mfma_f32_16x16x32_bf16(afrag[3][kk], b, cc[3], 0, 0, 0);
            }
            const int n = colbase + s * 32 + st * 16 + l15;
            const bool okc  = n < NTOT;
            const bool isbg = n < NBG;
            #pragma unroll
            for (int q = 0; q < 4; ++q) {
                #pragma unroll
                for (int r = 0; r < 4; ++r) {
                    float e = exp2f(cc[q][r] * SCALE_LOG2E);
                    e = okc ? e : 0.f;
                    pbg[q * 4 + r] += isbg ? e : 0.f;
                    pnb[q * 4 + r] += isbg ? 0.f : e;
                }
            }
        }
    }

    #pragma unroll
    for (int off = 1; off < 16; off <<= 1) {
        #pragma unroll
        for (int i = 0; i < 16; ++i) {
            pbg[i] += __shfl_xor(pbg[i], off);
            pnb[i] += __shfl_xor(pnb[i], off);
        }
    }
    if (l15 == 0) {
        #pragma unroll
        for (int q = 0; q < 4; ++q) {
            #pragma unroll
            for (int r = 0; r < 4; ++r) {
                const int row = rowbase + wave * 64 + q * 16 + quad * 4 + r;
                atomic_add_f(&sum_bg[row], pbg[q * 4 + r]);
                atomic_add_f(&sum_nb[row], pnb[q * 4 + r]);
            }
        }
    }
}

// -------- Stage 2: finalize (128 blocks; wave = 8 rows) + scalar fold ------
__global__ __launch_bounds__(256) void finalize_kernel(
    const float* __restrict__ inputs, const int* __restrict__ roi_label,
    const float* __restrict__ lut,
    const float* __restrict__ sum_bg, const float* __restrict__ sum_nb,
    float* __restrict__ accums, unsigned int* __restrict__ ticket,
    float* __restrict__ out)
{
    __shared__ float s_det[4], s_oim[4], s_nv[4];
    const int wid  = threadIdx.x >> 6;
    const int lane = threadIdx.x & 63;

    float det_a = 0.f, oim_a = 0.f, nv_a = 0.f;

    #pragma unroll 1
    for (int it = 0; it < 8; ++it) {
        const int row = blockIdx.x * 32 + wid * 8 + it;
        const int r   = roi_label[row];

        float dot = 0.f;
        {
            const int rc = r < 0 ? 0 : r;
            const f32x4 xi = *(const f32x4*)(inputs + (size_t)row * FEAT + lane * 4);
            const f32x4 li = *(const f32x4*)(lut + (size_t)rc * FEAT + lane * 4);
            #pragma unroll
            for (int jj = 0; jj < 4; ++jj) {
                float a = __bfloat162float(__float2bfloat16(xi[jj]));
                float b = __bfloat162float(__float2bfloat16(li[jj]));
                dot += a * b;
            }
        }
        #pragma unroll
        for (int off = 32; off > 0; off >>= 1) dot += __shfl_xor(dot, off);

        if (lane == 0) {
            const float sbg = sum_bg[row];
            const float snb = sum_nb[row];
            const float inv = 1.f / (sbg + snb);
            const float cls0 = sbg * inv;
            const float cls1 = snb * inv;
            out[2 * row]     = cls0;
            out[2 * row + 1] = cls1;

            const float cs = (r >= -1) ? cls1 : cls0;
            const float om = 1.f - cs;
            det_a += -(0.25f * om * om * logf(cs)) * (1.f / (float)BATCH);
            nv_a  += (r >= -1) ? 1.f : 0.f;

            if (r >= 0) {
                const float slab = 30.f * dot;
                const float logp = slab - logf(snb);
                const float p    = expf(logp);
                const float om2  = 1.f - p;
                oim_a += -(0.25f * om2 * om2 * logp) * cls1 * cls1;
            }
        }
    }

    if (lane == 0) { s_det[wid] = det_a; s_oim[wid] = oim_a; s_nv[wid] = nv_a; }
    __syncthreads();
    if (threadIdx.x == 0) {
        atomic_add_f(&accums[0], s_det[0] + s_det[1] + s_det[2] + s_det[3]);
        atomic_add_f(&accums[1], s_oim[0] + s_oim[1] + s_oim[2] + s_oim[3]);
        atomic_add_f(&accums[2], s_nv[0] + s_nv[1] + s_nv[2] + s_nv[3]);
        __threadfence();
        const unsigned t = __hip_atomic_fetch_add(ticket, 1u, __ATOMIC_ACQ_REL,
                                                  __HIP_MEMORY_SCOPE_AGENT);
        if (t == gridDim.x - 1) {
            const float det = __hip_atomic_load(&accums[0], __ATOMIC_RELAXED, __HIP_MEMORY_SCOPE_AGENT);
            const float oim = __hip_atomic_load(&accums[1], __ATOMIC_RELAXED, __HIP_MEMORY_SCOPE_AGENT);
            float nv        = __hip_atomic_load(&accums[2], __ATOMIC_RELAXED, __HIP_MEMORY_SCOPE_AGENT);
            if (nv < 1.f) nv = 1.f;
            out[2 * BATCH]     = det;
            out[2 * BATCH + 1] = oim / nv;
        }
    }
}

extern "C" void kernel_launch(void* const* d_in, const int* in_sizes, int n_in,
                              void* d_out, int out_size, void* d_ws, size_t ws_size,
                              hipStream_t stream)
{
    const float* inputs = (const float*)d_in[0];
    const int*   roi    = (const int*)d_in[1];
    const float* lut    = (const float*)d_in[2];
    const float* cq     = (const float*)d_in[3];
    const float* cqb    = (const float*)d_in[4];
    float* out = (float*)d_out;

    if (ws_size >= (size_t)WS_NEED) {
        u16* tabt = (u16*)d_ws;
        u16* at   = (u16*)((char*)d_ws + TABT_BYTES);
        float* S  = (float*)((char*)d_ws + SUMS_OFF);
        prepass_kernel<<<PRE_BLOCKS, 256, 0, stream>>>(inputs, lut, cq, cqb, tabt, at, S);
        score_bf16_kernel<<<976, 256, 0, stream>>>(tabt, at, S, S + BATCH);
        finalize_kernel<<<128, 256, 0, stream>>>(
            inputs, roi, lut, S, S + BATCH, S + 2 * BATCH,
            (unsigned int*)(S + 2 * BATCH + 3), out);
    } else {
        float* S = (float*)d_ws;
        hipMemsetAsync(S, 0, SUMS_FLOATS * sizeof(float), stream);
        dim3 g1(61, 16);
        score_f32_kernel<<<g1, 256, 0, stream>>>(inputs, lut, cq, cqb, S, S + BATCH);
        finalize_kernel<<<128, 256, 0, stream>>>(
            inputs, roi, lut, S, S + BATCH, S + 2 * BATCH,
            (unsigned int*)(S + 2 * BATCH + 3), out);
    }
}